// Round 8
// baseline (259.110 us; speedup 1.0000x reference)
//
#include <hip/hip_runtime.h>
#include <hip/hip_bf16.h>

#define BB 2
#define HH 56
#define WW 56
#define LL (HH*WW)          // 3136
#define DM 96
#define DI 192
#define NS 16               // d_state
#define DTR 6
#define KK 4
#define CDBL (DTR + 2*NS)   // 38
#define CS 32               // scan chunk size
#define NC 98               // number of chunks (CS*NC == LL)
#define ROWS (BB*KK*DI)     // 1536 state rows (x NS cols) per chunk

// ---------------- kernel 1: in_proj as tiled GEMM ----------------
#define IP_BM 32
__global__ __launch_bounds__(256) void k_inproj(const float* __restrict__ x,
                                                const float* __restrict__ w,
                                                float* __restrict__ xcpre,
                                                float* __restrict__ zsilu) {
    __shared__ float xl[IP_BM*100];
    __shared__ float wl[64*100];
    int t = threadIdx.x;
    int bl0 = blockIdx.x * IP_BM;
    for (int idx = t; idx < IP_BM*96; idx += 256) {
        int r = idx/96, c = idx%96;
        xl[r*100+c] = x[(bl0+r)*DM + c];
    }
    int pg = t >> 4, eg = t & 15;
    for (int nc = 0; nc < 6; ++nc) {
        __syncthreads();
        for (int idx = t; idx < 64*96; idx += 256) {
            int r = idx/96, c = idx%96;
            wl[r*100+c] = w[(nc*64+r)*DM + c];
        }
        __syncthreads();
        float acc[2][4] = {};
        #pragma unroll 4
        for (int k = 0; k < 96; ++k) {
            float a0 = xl[(pg*2+0)*100+k];
            float a1 = xl[(pg*2+1)*100+k];
            float b0 = wl[(eg*4+0)*100+k];
            float b1 = wl[(eg*4+1)*100+k];
            float b2 = wl[(eg*4+2)*100+k];
            float b3 = wl[(eg*4+3)*100+k];
            acc[0][0] = fmaf(a0,b0,acc[0][0]); acc[0][1] = fmaf(a0,b1,acc[0][1]);
            acc[0][2] = fmaf(a0,b2,acc[0][2]); acc[0][3] = fmaf(a0,b3,acc[0][3]);
            acc[1][0] = fmaf(a1,b0,acc[1][0]); acc[1][1] = fmaf(a1,b1,acc[1][1]);
            acc[1][2] = fmaf(a1,b2,acc[1][2]); acc[1][3] = fmaf(a1,b3,acc[1][3]);
        }
        #pragma unroll
        for (int j = 0; j < 2; ++j) {
            int bl = bl0 + pg*2 + j;
            #pragma unroll
            for (int jj = 0; jj < 4; ++jj) {
                int e = nc*64 + eg*4 + jj;
                float v = acc[j][jj];
                if (e < DI) xcpre[(size_t)bl*DI + e] = v;
                else        zsilu[(size_t)bl*DI + (e-DI)] = v / (1.f + expf(-v));
            }
        }
    }
}

// ------------- kernel 2: depthwise 3x3 conv + bias + silu + scan scatter -------------
__global__ __launch_bounds__(DI) void k_conv(const float* __restrict__ xcpre,
                                             const float* __restrict__ cw,
                                             const float* __restrict__ cb,
                                             float* __restrict__ xs0,
                                             float* __restrict__ xs1) {
    int bl = blockIdx.x;
    int b = bl / LL, l = bl % LL;
    int h = l / WW, w = l % WW;
    int c = threadIdx.x;
    float acc = cb[c];
    #pragma unroll
    for (int dh = -1; dh <= 1; ++dh) {
        int hh = h + dh;
        if (hh < 0 || hh >= HH) continue;
        #pragma unroll
        for (int dw = -1; dw <= 1; ++dw) {
            int ww2 = w + dw;
            if (ww2 < 0 || ww2 >= WW) continue;
            acc = fmaf(xcpre[(b*LL + hh*WW + ww2)*DI + c],
                       cw[c*9 + (dh+1)*3 + (dw+1)], acc);
        }
    }
    float v = acc / (1.f + expf(-acc));   // silu
    int i  = (w & 1) ? (HH-1-h) : h;
    int l0 = i*WW + w;
    int l1 = ((i & 1) ? (WW-1-w) : w)*HH + i;
    xs0[(b*LL + l0)*DI + c] = v;
    xs1[(b*LL + l1)*DI + c] = v;
}

// ------------- kernel 3: x_proj + dt_proj + softplus (grid-occupancy tuned) -------------
// TL=32 positions/block -> grid (98,4,2)=784 blocks (~3 blocks/CU, ~12 waves/CU).
// K staged in 4 chunks of 48 ch (LDS ~15.6KB). Phase 1: 3c x 2ll micro-tile, one pass.
// Phase 2: all 256 threads, 24 outputs each, static-unrolled register cache.
#define TL 32
#define KCH 48
#define NKC 4
#define XSTR 52
#define WSTR 52
__global__ __launch_bounds__(256) void k_proj(const float* __restrict__ xs0,
                                              const float* __restrict__ xs1,
                                              const float* __restrict__ xpw,   // (K,38,192)
                                              const float* __restrict__ dtw,   // (K,192,6)
                                              const float* __restrict__ dtb,   // (K,192)
                                              float* __restrict__ delta,
                                              float* __restrict__ Bsb,
                                              float* __restrict__ Csb) {
    int tile = blockIdx.x, k = blockIdx.y, b = blockIdx.z;
    int bk = b*KK + k;
    int t = threadIdx.x;
    __shared__ float Xl[TL*XSTR];      // 32 x 48-chunk, stride 52
    __shared__ float Wl[39*WSTR];      // 38 rows + 1 junk (c=38), stride 52
    __shared__ float dblL[DTR*36];     // dt rows, 32 + pad

    const float* src = (k & 1) ? xs1 : xs0;
    const bool rev = (k >= 2);
    int cp = t >> 4, lp = t & 15;      // cp 0..15 (only <13 compute), lp 0..15

    float acc[3][2] = {};
    for (int kc = 0; kc < NKC; ++kc) {
        __syncthreads();
        // stage Wl (39 rows x 12 float4; row 38 zero)
        for (int idx = t; idx < 39*12; idx += 256) {
            int r = idx/12, q = idx%12;
            float4 v = (r < CDBL)
                ? ((const float4*)(xpw + (size_t)k*CDBL*DI + (size_t)r*DI + kc*KCH))[q]
                : make_float4(0.f,0.f,0.f,0.f);
            *(float4*)&Wl[r*WSTR + 4*q] = v;
        }
        // stage Xl (32 rows x 12 float4)
        for (int idx = t; idx < TL*12; idx += 256) {
            int ll = idx/12, q = idx%12;
            int lg = tile*TL + ll;
            int lpos = rev ? (LL-1-lg) : lg;
            *(float4*)&Xl[ll*XSTR + 4*q] =
                ((const float4*)(src + (size_t)(b*LL + lpos)*DI + kc*KCH))[q];
        }
        __syncthreads();
        if (cp < 13) {
            const float4* w0 = (const float4*)&Wl[(3*cp+0)*WSTR];
            const float4* w1 = (const float4*)&Wl[(3*cp+1)*WSTR];
            const float4* w2 = (const float4*)&Wl[(3*cp+2)*WSTR];
            const float4* x0 = (const float4*)&Xl[(lp    )*XSTR];
            const float4* x1 = (const float4*)&Xl[(lp+16)*XSTR];
            #pragma unroll
            for (int q = 0; q < 12; ++q) {
                float4 wa = w0[q], wb = w1[q], wc = w2[q];
                float4 xa = x0[q], xb = x1[q];
                acc[0][0]=fmaf(wa.x,xa.x,acc[0][0]); acc[0][0]=fmaf(wa.y,xa.y,acc[0][0]);
                acc[0][0]=fmaf(wa.z,xa.z,acc[0][0]); acc[0][0]=fmaf(wa.w,xa.w,acc[0][0]);
                acc[0][1]=fmaf(wa.x,xb.x,acc[0][1]); acc[0][1]=fmaf(wa.y,xb.y,acc[0][1]);
                acc[0][1]=fmaf(wa.z,xb.z,acc[0][1]); acc[0][1]=fmaf(wa.w,xb.w,acc[0][1]);
                acc[1][0]=fmaf(wb.x,xa.x,acc[1][0]); acc[1][0]=fmaf(wb.y,xa.y,acc[1][0]);
                acc[1][0]=fmaf(wb.z,xa.z,acc[1][0]); acc[1][0]=fmaf(wb.w,xa.w,acc[1][0]);
                acc[1][1]=fmaf(wb.x,xb.x,acc[1][1]); acc[1][1]=fmaf(wb.y,xb.y,acc[1][1]);
                acc[1][1]=fmaf(wb.z,xb.z,acc[1][1]); acc[1][1]=fmaf(wb.w,xb.w,acc[1][1]);
                acc[2][0]=fmaf(wc.x,xa.x,acc[2][0]); acc[2][0]=fmaf(wc.y,xa.y,acc[2][0]);
                acc[2][0]=fmaf(wc.z,xa.z,acc[2][0]); acc[2][0]=fmaf(wc.w,xa.w,acc[2][0]);
                acc[2][1]=fmaf(wc.x,xb.x,acc[2][1]); acc[2][1]=fmaf(wc.y,xb.y,acc[2][1]);
                acc[2][1]=fmaf(wc.z,xb.z,acc[2][1]); acc[2][1]=fmaf(wc.w,xb.w,acc[2][1]);
            }
        }
    }
    // scatter outputs
    if (cp < 13) {
        #pragma unroll
        for (int ci = 0; ci < 3; ++ci) {
            int c = 3*cp + ci;
            if (c < CDBL) {
                #pragma unroll
                for (int li = 0; li < 2; ++li) {
                    int ll = lp + 16*li;
                    int lg = tile*TL + ll;
                    float v = acc[ci][li];
                    if (c < DTR)          dblL[c*36 + ll] = v;
                    else if (c < DTR+NS)  Bsb[((size_t)bk*LL + lg)*NS + (c-DTR)] = v;
                    else                  Csb[((size_t)bk*LL + lg)*NS + (c-DTR-NS)] = v;
                }
            }
        }
    }
    __syncthreads();

    // phase 2: delta (32 x 192 outputs, all 256 threads, 24 each)
    float wr0[DTR], wr1[DTR], wr2[DTR], bb0, bb1, bb2;
    {
        int d0 = t % DI, d1 = (t+64) % DI, d2 = (t+128) % DI;
        #pragma unroll
        for (int r = 0; r < DTR; ++r) {
            wr0[r] = dtw[((size_t)k*DI + d0)*DTR + r];
            wr1[r] = dtw[((size_t)k*DI + d1)*DTR + r];
            wr2[r] = dtw[((size_t)k*DI + d2)*DTR + r];
        }
        bb0 = dtb[k*DI + d0]; bb1 = dtb[k*DI + d1]; bb2 = dtb[k*DI + d2];
    }
    float* dbase = delta + ((size_t)bk*LL + (size_t)tile*TL)*DI;
    for (int j3 = 0; j3 < 8; ++j3) {
        #pragma unroll
        for (int jj = 0; jj < 3; ++jj) {
            int j = j3*3 + jj;
            int idx = t + 256*j;
            int d = idx % DI;
            int ll = idx / DI;
            float a = (jj == 0) ? bb0 : (jj == 1) ? bb1 : bb2;
            const float* wrp = (jj == 0) ? wr0 : (jj == 1) ? wr1 : wr2;
            #pragma unroll
            for (int r = 0; r < DTR; ++r) a = fmaf(wrp[r], dblL[r*36 + ll], a);
            float sp = fmaxf(a, 0.f) + log1pf(expf(-fabsf(a)));
            dbase[(size_t)ll*DI + d] = sp;
        }
    }
}

// ------------- kernel 4a: chunked scan pass 1 — thread = d, 16 n-states in regs -------------
__global__ __launch_bounds__(192) void k_scan1(const float* __restrict__ delta,
                                               const float* __restrict__ xs0,
                                               const float* __restrict__ xs1,
                                               const float* __restrict__ Bsb,
                                               const float* __restrict__ A_logs,
                                               float* __restrict__ P,     // [c][bk*DI+d][n]
                                               float* __restrict__ Hend) {
    int c = blockIdx.x, bk = blockIdx.y;
    int k = bk & 3, b = bk >> 2;
    int d = threadIdx.x;
    int kd = k*DI + d;
    __shared__ float Bl[CS*NS];
    const float* bsrc = Bsb + ((size_t)bk*LL + c*CS)*NS;
    for (int i = threadIdx.x; i < CS*NS/4; i += 192)
        ((float4*)Bl)[i] = ((const float4*)bsrc)[i];

    float A[NS], h[NS], p[NS];
    #pragma unroll
    for (int q = 0; q < 4; ++q) {
        float4 av = *(const float4*)&A_logs[kd*NS + 4*q];
        A[4*q+0] = -expf(av.x); A[4*q+1] = -expf(av.y);
        A[4*q+2] = -expf(av.z); A[4*q+3] = -expf(av.w);
    }
    #pragma unroll
    for (int n = 0; n < NS; ++n) { h[n] = 0.f; p[n] = 1.f; }
    __syncthreads();

    const bool rev = (k >= 2);
    const float* dp = delta + ((size_t)bk*LL + c*CS)*DI + d;
    const float* up = ((k & 1) ? xs1 : xs0) + (size_t)b*LL*DI + d;
    const int l0 = c*CS;

    #pragma unroll 2
    for (int i = 0; i < CS; ++i) {
        float dt = dp[(size_t)i*DI];
        int lp = rev ? (LL-1-(l0+i)) : (l0+i);
        float u = up[(size_t)lp*DI];
        float dtu = dt * u;
        float Bv[NS];
        #pragma unroll
        for (int q = 0; q < 4; ++q)
            *(float4*)&Bv[4*q] = *(const float4*)&Bl[i*NS + 4*q];
        #pragma unroll
        for (int n = 0; n < NS; ++n) {
            float dA = __expf(dt * A[n]);
            h[n] = fmaf(dA, h[n], dtu * Bv[n]);
            p[n] *= dA;
        }
    }
    size_t obase = ((size_t)c*ROWS + bk*DI + d)*NS;
    #pragma unroll
    for (int q = 0; q < 4; ++q) {
        *(float4*)&P[obase + 4*q]    = make_float4(p[4*q], p[4*q+1], p[4*q+2], p[4*q+3]);
        *(float4*)&Hend[obase + 4*q] = make_float4(h[4*q], h[4*q+1], h[4*q+2], h[4*q+3]);
    }
}

// ------------- kernel 4b: combine chunk states sequentially -------------
__global__ __launch_bounds__(256) void k_scanmid(const float* __restrict__ P,
                                                 const float* __restrict__ Hend,
                                                 float* __restrict__ Hin) {
    int tid = blockIdx.x*256 + threadIdx.x;     // 0 .. ROWS*NS-1
    float h = 0.f;
    for (int c = 0; c < NC; ++c) {
        size_t idx = (size_t)c*(ROWS*NS) + tid;
        Hin[idx] = h;
        h = fmaf(P[idx], h, Hend[idx]);
    }
}

// ------------- kernel 4c: chunked scan pass 2 — rescan with true h_in, emit y -------------
__global__ __launch_bounds__(192) void k_scan2(const float* __restrict__ delta,
                                               const float* __restrict__ xs0,
                                               const float* __restrict__ xs1,
                                               const float* __restrict__ Bsb,
                                               const float* __restrict__ Csb,
                                               const float* __restrict__ A_logs,
                                               const float* __restrict__ Ds,
                                               const float* __restrict__ Hin,
                                               float* __restrict__ oy) {
    int c = blockIdx.x, bk = blockIdx.y;
    int k = bk & 3, b = bk >> 2;
    int d = threadIdx.x;
    int kd = k*DI + d;
    __shared__ float Bl[CS*NS];
    __shared__ float Cl[CS*NS];
    const float* bsrc = Bsb + ((size_t)bk*LL + c*CS)*NS;
    const float* csrc = Csb + ((size_t)bk*LL + c*CS)*NS;
    for (int i = threadIdx.x; i < CS*NS/4; i += 192) {
        ((float4*)Bl)[i] = ((const float4*)bsrc)[i];
        ((float4*)Cl)[i] = ((const float4*)csrc)[i];
    }

    float A[NS], h[NS];
    #pragma unroll
    for (int q = 0; q < 4; ++q) {
        float4 av = *(const float4*)&A_logs[kd*NS + 4*q];
        A[4*q+0] = -expf(av.x); A[4*q+1] = -expf(av.y);
        A[4*q+2] = -expf(av.z); A[4*q+3] = -expf(av.w);
    }
    size_t ibase = ((size_t)c*ROWS + bk*DI + d)*NS;
    #pragma unroll
    for (int q = 0; q < 4; ++q) {
        float4 hv = *(const float4*)&Hin[ibase + 4*q];
        h[4*q+0] = hv.x; h[4*q+1] = hv.y; h[4*q+2] = hv.z; h[4*q+3] = hv.w;
    }
    const float Dv = Ds[kd];
    __syncthreads();

    const bool rev = (k >= 2);
    const float* dp = delta + ((size_t)bk*LL + c*CS)*DI + d;
    const float* up = ((k & 1) ? xs1 : xs0) + (size_t)b*LL*DI + d;
    float* yp = oy + ((size_t)bk*LL + c*CS)*DI + d;
    const int l0 = c*CS;

    #pragma unroll 2
    for (int i = 0; i < CS; ++i) {
        float dt = dp[(size_t)i*DI];
        int lp = rev ? (LL-1-(l0+i)) : (l0+i);
        float u = up[(size_t)lp*DI];
        float dtu = dt * u;
        float Bv[NS], Cv[NS];
        #pragma unroll
        for (int q = 0; q < 4; ++q) {
            *(float4*)&Bv[4*q] = *(const float4*)&Bl[i*NS + 4*q];
            *(float4*)&Cv[4*q] = *(const float4*)&Cl[i*NS + 4*q];
        }
        float acc = 0.f;
        #pragma unroll
        for (int n = 0; n < NS; ++n) {
            float dA = __expf(dt * A[n]);
            h[n] = fmaf(dA, h[n], dtu * Bv[n]);
            acc = fmaf(h[n], Cv[n], acc);
        }
        yp[(size_t)i*DI] = fmaf(u, Dv, acc);
    }
}

// ------------- kernel 5: gather + LayerNorm + gate, then tiled GEMM out_proj -------------
#define OP_BM 32
__global__ __launch_bounds__(256) void k_out(const float* __restrict__ oy,
                                             const float* __restrict__ zsilu,
                                             const float* __restrict__ onw,
                                             const float* __restrict__ onb,
                                             const float* __restrict__ opw,
                                             float* __restrict__ out) {
    __shared__ float yv[OP_BM*196];
    __shared__ float wl[96*68];
    int t = threadIdx.x;
    int bl0 = blockIdx.x * OP_BM;
    int lane = t & 63, wv = t >> 6;

    for (int pp = 0; pp < 8; ++pp) {
        int p = wv*8 + pp;
        int bl = bl0 + p;
        int b = bl / LL, l = bl % LL;
        int h = l / WW, w2 = l % WW;
        int i = (w2 & 1) ? (HH-1-h) : h;
        int l0 = i*WW + w2;
        int l1 = ((i & 1) ? (WW-1-w2) : w2)*HH + i;
        size_t base = (size_t)b*KK*LL*DI;
        float yd[3]; float s1 = 0.f, s2 = 0.f;
        #pragma unroll
        for (int j = 0; j < 3; ++j) {
            int c = lane + j*64;
            float v = oy[base + (size_t)(0*LL + l0)*DI + c]
                    + oy[base + (size_t)(1*LL + l1)*DI + c]
                    + oy[base + (size_t)(2*LL + (LL-1-l0))*DI + c]
                    + oy[base + (size_t)(3*LL + (LL-1-l1))*DI + c];
            yd[j] = v; s1 += v; s2 += v*v;
        }
        #pragma unroll
        for (int m = 1; m < 64; m <<= 1) { s1 += __shfl_xor(s1, m); s2 += __shfl_xor(s2, m); }
        float mu  = s1 / DI;
        float var = s2 / DI - mu*mu;
        float ry  = rsqrtf(var + 1e-5f);
        #pragma unroll
        for (int j = 0; j < 3; ++j) {
            int c = lane + j*64;
            float yn = (yd[j] - mu) * ry * onw[c] + onb[c];
            yv[p*196 + c] = yn * zsilu[(size_t)bl*DI + c];
        }
    }

    int pg = t >> 5, eg = t & 31;
    float acc[4][3] = {};
    for (int kc = 0; kc < 3; ++kc) {
        __syncthreads();
        for (int idx = t; idx < 96*64; idx += 256) {
            int r = idx >> 6, c = idx & 63;
            wl[r*68 + c] = opw[r*DI + kc*64 + c];
        }
        __syncthreads();
        #pragma unroll 4
        for (int kk = 0; kk < 64; ++kk) {
            float a[4], bq[3];
            #pragma unroll
            for (int j = 0; j < 4; ++j)  a[j]  = yv[(pg*4+j)*196 + kc*64 + kk];
            #pragma unroll
            for (int jj = 0; jj < 3; ++jj) bq[jj] = wl[(eg*3+jj)*68 + kk];
            #pragma unroll
            for (int j = 0; j < 4; ++j)
                #pragma unroll
                for (int jj = 0; jj < 3; ++jj)
                    acc[j][jj] = fmaf(a[j], bq[jj], acc[j][jj]);
        }
    }
    #pragma unroll
    for (int j = 0; j < 4; ++j) {
        int bl = bl0 + pg*4 + j;
        #pragma unroll
        for (int jj = 0; jj < 3; ++jj)
            out[(size_t)bl*DM + eg*3 + jj] = acc[j][jj];
    }
}

extern "C" void kernel_launch(void* const* d_in, const int* in_sizes, int n_in,
                              void* d_out, int out_size, void* d_ws, size_t ws_size,
                              hipStream_t stream) {
    const float* x      = (const float*)d_in[0];
    const float* ipw    = (const float*)d_in[1];
    const float* convw  = (const float*)d_in[2];
    const float* convb  = (const float*)d_in[3];
    const float* xpw    = (const float*)d_in[4];
    const float* dtw    = (const float*)d_in[5];
    const float* dtb    = (const float*)d_in[6];
    const float* A_logs = (const float*)d_in[7];
    const float* Ds     = (const float*)d_in[8];
    const float* onw    = (const float*)d_in[9];
    const float* onb    = (const float*)d_in[10];
    const float* opw    = (const float*)d_in[11];
    float* out = (float*)d_out;

    float* ws = (float*)d_ws;
    const size_t SZ_BLD  = (size_t)BB*LL*DI;          // 1,204,224
    const size_t SZ_BKLD = (size_t)BB*KK*LL*DI;       // 4,816,896
    const size_t SZ_BKLN = (size_t)BB*KK*LL*NS;       //   401,408
    const size_t SZ_ST   = (size_t)NC*ROWS*NS;        // 2,408,448
    float* xcpre = ws;
    float* zsilu = xcpre + SZ_BLD;
    float* xs0   = zsilu + SZ_BLD;
    float* xs1   = xs0   + SZ_BLD;
    float* delta = xs1   + SZ_BLD;
    float* Bsb   = delta + SZ_BKLD;
    float* Csb   = Bsb   + SZ_BKLN;
    float* oy    = Csb   + SZ_BKLN;
    float* Hin   = oy    + SZ_BKLD;
    float* Hend  = oy;                // alias: dead before oy written (scan2)
    float* P     = oy + SZ_ST;        // alias: 2*SZ_ST == SZ_BKLD, fits exactly

    k_inproj<<<(BB*LL)/IP_BM, 256, 0, stream>>>(x, ipw, xcpre, zsilu);
    k_conv<<<BB*LL, DI, 0, stream>>>(xcpre, convw, convb, xs0, xs1);
    dim3 g3(LL/TL, KK, BB);
    k_proj<<<g3, 256, 0, stream>>>(xs0, xs1, xpw, dtw, dtb, delta, Bsb, Csb);
    dim3 gs(NC, BB*KK);
    k_scan1<<<gs, 192, 0, stream>>>(delta, xs0, xs1, Bsb, A_logs, P, Hend);
    k_scanmid<<<(ROWS*NS)/256, 256, 0, stream>>>(P, Hend, Hin);
    k_scan2<<<gs, 192, 0, stream>>>(delta, xs0, xs1, Bsb, Csb, A_logs, Ds, Hin, oy);
    k_out<<<(BB*LL)/OP_BM, 256, 0, stream>>>(oy, zsilu, onw, onb, opw, out);
}

// Round 10
// 244.458 us; speedup vs baseline: 1.0599x; 1.0599x over previous
//
#include <hip/hip_runtime.h>
#include <hip/hip_bf16.h>

#define BB 2
#define HH 56
#define WW 56
#define LL (HH*WW)          // 3136
#define DM 96
#define DI 192
#define NS 16               // d_state
#define DTR 6
#define KK 4
#define CDBL (DTR + 2*NS)   // 38
#define CS 32               // scan chunk size
#define NC 98               // number of chunks (CS*NC == LL)
#define ROWS (BB*KK*DI)     // 1536 state rows (x NS cols) per chunk

// ---------------- kernel 1: in_proj as tiled GEMM (float4 LDS, no div) ----------------
#define IP_BM 32
__global__ __launch_bounds__(256) void k_inproj(const float* __restrict__ x,
                                                const float* __restrict__ w,
                                                float* __restrict__ xcpre,
                                                float* __restrict__ zsilu) {
    __shared__ float xl[IP_BM*100];   // [pos][96], stride 100
    __shared__ float wl[64*100];      // j-interleaved: w-row r at lds row (r&3)*16+(r>>2)
    int t = threadIdx.x;
    int bl0 = blockIdx.x * IP_BM;
    int qs = t & 31;                  // staging q (0..23 active)
    // stage xl: 32 rows x 24 float4
    for (int r = t >> 5; r < IP_BM; r += 8)
        if (qs < 24)
            *(float4*)&xl[r*100 + 4*qs] = *(const float4*)&x[(size_t)(bl0+r)*DM + 4*qs];
    int pg = t >> 4, eg = t & 15;     // pg: 2 positions, eg: 4 channels (eg*4+j)
    for (int nc = 0; nc < 6; ++nc) {
        __syncthreads();
        for (int r = t >> 5; r < 64; r += 8)
            if (qs < 24)
                *(float4*)&wl[((r&3)*16 + (r>>2))*100 + 4*qs] =
                    *(const float4*)&w[(size_t)(nc*64+r)*DM + 4*qs];
        __syncthreads();
        float acc[2][4] = {};
        const float4* xa4 = (const float4*)&xl[(pg*2+0)*100];
        const float4* xb4 = (const float4*)&xl[(pg*2+1)*100];
        const float4* w0 = (const float4*)&wl[(0*16+eg)*100];
        const float4* w1 = (const float4*)&wl[(1*16+eg)*100];
        const float4* w2 = (const float4*)&wl[(2*16+eg)*100];
        const float4* w3 = (const float4*)&wl[(3*16+eg)*100];
        #pragma unroll 6
        for (int q = 0; q < 24; ++q) {
            float4 xa = xa4[q], xb = xb4[q];
            float4 b0 = w0[q], b1 = w1[q], b2 = w2[q], b3 = w3[q];
            acc[0][0]=fmaf(xa.x,b0.x,acc[0][0]); acc[0][0]=fmaf(xa.y,b0.y,acc[0][0]);
            acc[0][0]=fmaf(xa.z,b0.z,acc[0][0]); acc[0][0]=fmaf(xa.w,b0.w,acc[0][0]);
            acc[0][1]=fmaf(xa.x,b1.x,acc[0][1]); acc[0][1]=fmaf(xa.y,b1.y,acc[0][1]);
            acc[0][1]=fmaf(xa.z,b1.z,acc[0][1]); acc[0][1]=fmaf(xa.w,b1.w,acc[0][1]);
            acc[0][2]=fmaf(xa.x,b2.x,acc[0][2]); acc[0][2]=fmaf(xa.y,b2.y,acc[0][2]);
            acc[0][2]=fmaf(xa.z,b2.z,acc[0][2]); acc[0][2]=fmaf(xa.w,b2.w,acc[0][2]);
            acc[0][3]=fmaf(xa.x,b3.x,acc[0][3]); acc[0][3]=fmaf(xa.y,b3.y,acc[0][3]);
            acc[0][3]=fmaf(xa.z,b3.z,acc[0][3]); acc[0][3]=fmaf(xa.w,b3.w,acc[0][3]);
            acc[1][0]=fmaf(xb.x,b0.x,acc[1][0]); acc[1][0]=fmaf(xb.y,b0.y,acc[1][0]);
            acc[1][0]=fmaf(xb.z,b0.z,acc[1][0]); acc[1][0]=fmaf(xb.w,b0.w,acc[1][0]);
            acc[1][1]=fmaf(xb.x,b1.x,acc[1][1]); acc[1][1]=fmaf(xb.y,b1.y,acc[1][1]);
            acc[1][1]=fmaf(xb.z,b1.z,acc[1][1]); acc[1][1]=fmaf(xb.w,b1.w,acc[1][1]);
            acc[1][2]=fmaf(xb.x,b2.x,acc[1][2]); acc[1][2]=fmaf(xb.y,b2.y,acc[1][2]);
            acc[1][2]=fmaf(xb.z,b2.z,acc[1][2]); acc[1][2]=fmaf(xb.w,b2.w,acc[1][2]);
            acc[1][3]=fmaf(xb.x,b3.x,acc[1][3]); acc[1][3]=fmaf(xb.y,b3.y,acc[1][3]);
            acc[1][3]=fmaf(xb.z,b3.z,acc[1][3]); acc[1][3]=fmaf(xb.w,b3.w,acc[1][3]);
        }
        #pragma unroll
        for (int j = 0; j < 2; ++j) {
            int bl = bl0 + pg*2 + j;
            #pragma unroll
            for (int jj = 0; jj < 4; ++jj) {
                int e = nc*64 + eg*4 + jj;
                float v = acc[j][jj];
                if (e < DI) xcpre[(size_t)bl*DI + e] = v;
                else        zsilu[(size_t)bl*DI + (e-DI)] = v / (1.f + __expf(-v));
            }
        }
    }
}

// ------------- kernel 2: depthwise 3x3 conv + silu + scan scatter (no div) -------------
__global__ __launch_bounds__(DI) void k_conv(const float* __restrict__ xcpre,
                                             const float* __restrict__ cw,
                                             const float* __restrict__ cb,
                                             float* __restrict__ xs0,
                                             float* __restrict__ xs1) {
    int w = blockIdx.x, h = blockIdx.y, b = blockIdx.z;
    int c = threadIdx.x;
    const float* src = xcpre + ((size_t)(b*LL + h*WW + w))*DI + c;
    const float* cwc = cw + c*9;
    float acc = cb[c];
    if (h > 0) {
        if (w > 0)      acc = fmaf(src[-(WW+1)*DI], cwc[0], acc);
                        acc = fmaf(src[-WW*DI],     cwc[1], acc);
        if (w < WW-1)   acc = fmaf(src[-(WW-1)*DI], cwc[2], acc);
    }
    {
        if (w > 0)      acc = fmaf(src[-DI],        cwc[3], acc);
                        acc = fmaf(src[0],          cwc[4], acc);
        if (w < WW-1)   acc = fmaf(src[DI],         cwc[5], acc);
    }
    if (h < HH-1) {
        if (w > 0)      acc = fmaf(src[(WW-1)*DI],  cwc[6], acc);
                        acc = fmaf(src[WW*DI],      cwc[7], acc);
        if (w < WW-1)   acc = fmaf(src[(WW+1)*DI],  cwc[8], acc);
    }
    float v = acc / (1.f + __expf(-acc));   // silu
    int i  = (w & 1) ? (HH-1-h) : h;
    int l0 = i*WW + w;
    int l1 = ((i & 1) ? (WW-1-w) : w)*HH + i;
    xs0[((size_t)b*LL + l0)*DI + c] = v;
    xs1[((size_t)b*LL + l1)*DI + c] = v;
}

// ------------- kernel 3: x_proj + dt_proj + softplus (overhead-stripped) -------------
#define TL 32
#define KCH 48
#define NKC 4
#define LSTR 52
__global__ __launch_bounds__(256) void k_proj(const float* __restrict__ xs0,
                                              const float* __restrict__ xs1,
                                              const float* __restrict__ xpw,   // (K,38,192)
                                              const float* __restrict__ dtw,   // (K,192,6)
                                              const float* __restrict__ dtb,   // (K,192)
                                              float* __restrict__ delta,
                                              float* __restrict__ Bsb,
                                              float* __restrict__ Csb) {
    int tile = blockIdx.x, k = blockIdx.y, b = blockIdx.z;
    int bk = b*KK + k;
    int t = threadIdx.x;
    __shared__ float Xl[TL*LSTR];
    __shared__ float Wl[39*LSTR];
    __shared__ float dblL[DTR*36];

    const float* src = (k & 1) ? xs1 : xs0;
    const bool rev = (k >= 2);
    int cp = t >> 4, lp = t & 15;
    int qs = t & 15;                  // staging q (0..11 active)

    float acc[3][2] = {};
    for (int kc = 0; kc < NKC; ++kc) {
        __syncthreads();
        // stage Wl: 39 rows x 12 float4 (row 38 zero) — shift/mask indexing
        for (int r = t >> 4; r < 39; r += 16)
            if (qs < 12) {
                float4 v = (r < CDBL)
                    ? *(const float4*)&xpw[(size_t)k*CDBL*DI + (size_t)r*DI + kc*KCH + 4*qs]
                    : make_float4(0.f,0.f,0.f,0.f);
                *(float4*)&Wl[r*LSTR + 4*qs] = v;
            }
        // stage Xl: 32 rows x 12 float4
        for (int r = t >> 4; r < TL; r += 16)
            if (qs < 12) {
                int lg = tile*TL + r;
                int lpos = rev ? (LL-1-lg) : lg;
                *(float4*)&Xl[r*LSTR + 4*qs] =
                    *(const float4*)&src[(size_t)(b*LL + lpos)*DI + kc*KCH + 4*qs];
            }
        __syncthreads();
        if (cp < 13) {
            const float4* w0 = (const float4*)&Wl[(3*cp+0)*LSTR];
            const float4* w1 = (const float4*)&Wl[(3*cp+1)*LSTR];
            const float4* w2 = (const float4*)&Wl[(3*cp+2)*LSTR];
            const float4* x0 = (const float4*)&Xl[(lp    )*LSTR];
            const float4* x1 = (const float4*)&Xl[(lp+16)*LSTR];
            #pragma unroll
            for (int q = 0; q < 12; ++q) {
                float4 wa = w0[q], wb = w1[q], wc = w2[q];
                float4 xa = x0[q], xb = x1[q];
                acc[0][0]=fmaf(wa.x,xa.x,acc[0][0]); acc[0][0]=fmaf(wa.y,xa.y,acc[0][0]);
                acc[0][0]=fmaf(wa.z,xa.z,acc[0][0]); acc[0][0]=fmaf(wa.w,xa.w,acc[0][0]);
                acc[0][1]=fmaf(wa.x,xb.x,acc[0][1]); acc[0][1]=fmaf(wa.y,xb.y,acc[0][1]);
                acc[0][1]=fmaf(wa.z,xb.z,acc[0][1]); acc[0][1]=fmaf(wa.w,xb.w,acc[0][1]);
                acc[1][0]=fmaf(wb.x,xa.x,acc[1][0]); acc[1][0]=fmaf(wb.y,xa.y,acc[1][0]);
                acc[1][0]=fmaf(wb.z,xa.z,acc[1][0]); acc[1][0]=fmaf(wb.w,xa.w,acc[1][0]);
                acc[1][1]=fmaf(wb.x,xb.x,acc[1][1]); acc[1][1]=fmaf(wb.y,xb.y,acc[1][1]);
                acc[1][1]=fmaf(wb.z,xb.z,acc[1][1]); acc[1][1]=fmaf(wb.w,xb.w,acc[1][1]);
                acc[2][0]=fmaf(wc.x,xa.x,acc[2][0]); acc[2][0]=fmaf(wc.y,xa.y,acc[2][0]);
                acc[2][0]=fmaf(wc.z,xa.z,acc[2][0]); acc[2][0]=fmaf(wc.w,xa.w,acc[2][0]);
                acc[2][1]=fmaf(wc.x,xb.x,acc[2][1]); acc[2][1]=fmaf(wc.y,xb.y,acc[2][1]);
                acc[2][1]=fmaf(wc.z,xb.z,acc[2][1]); acc[2][1]=fmaf(wc.w,xb.w,acc[2][1]);
            }
        }
    }
    if (cp < 13) {
        #pragma unroll
        for (int ci = 0; ci < 3; ++ci) {
            int c = 3*cp + ci;
            if (c < CDBL) {
                #pragma unroll
                for (int li = 0; li < 2; ++li) {
                    int ll = lp + 16*li;
                    int lg = tile*TL + ll;
                    float v = acc[ci][li];
                    if (c < DTR)          dblL[c*36 + ll] = v;
                    else if (c < DTR+NS)  Bsb[((size_t)bk*LL + lg)*NS + (c-DTR)] = v;
                    else                  Csb[((size_t)bk*LL + lg)*NS + (c-DTR-NS)] = v;
                }
            }
        }
    }
    __syncthreads();

    // phase 2: thread = d (192 active), acc[32] in regs, no div, fast softplus
    if (t < DI) {
        int d = t;
        float wr[DTR];
        #pragma unroll
        for (int r = 0; r < DTR; ++r) wr[r] = dtw[((size_t)k*DI + d)*DTR + r];
        float bias = dtb[k*DI + d];
        float a2[TL];
        #pragma unroll
        for (int ll = 0; ll < TL; ++ll) a2[ll] = bias;
        #pragma unroll
        for (int r = 0; r < DTR; ++r) {
            float wv = wr[r];
            const float4* db = (const float4*)&dblL[r*36];
            #pragma unroll
            for (int q = 0; q < 8; ++q) {
                float4 v = db[q];
                a2[4*q+0] = fmaf(wv, v.x, a2[4*q+0]);
                a2[4*q+1] = fmaf(wv, v.y, a2[4*q+1]);
                a2[4*q+2] = fmaf(wv, v.z, a2[4*q+2]);
                a2[4*q+3] = fmaf(wv, v.w, a2[4*q+3]);
            }
        }
        float* dst = delta + ((size_t)bk*LL + (size_t)tile*TL)*DI + d;
        #pragma unroll
        for (int ll = 0; ll < TL; ++ll) {
            float a = a2[ll];
            float sp = fmaxf(a, 0.f) + __logf(1.f + __expf(-fabsf(a)));
            dst[ll*DI] = sp;
        }
    }
}

// ------------- kernel 4a: chunked scan pass 1 — thread = d, 16 n-states in regs -------------
__global__ __launch_bounds__(192) void k_scan1(const float* __restrict__ delta,
                                               const float* __restrict__ xs0,
                                               const float* __restrict__ xs1,
                                               const float* __restrict__ Bsb,
                                               const float* __restrict__ A_logs,
                                               float* __restrict__ P,     // [c][bk*DI+d][n]
                                               float* __restrict__ Hend) {
    int c = blockIdx.x, bk = blockIdx.y;
    int k = bk & 3, b = bk >> 2;
    int d = threadIdx.x;
    int kd = k*DI + d;
    __shared__ float Bl[CS*NS];
    const float* bsrc = Bsb + ((size_t)bk*LL + c*CS)*NS;
    for (int i = threadIdx.x; i < CS*NS/4; i += 192)
        ((float4*)Bl)[i] = ((const float4*)bsrc)[i];

    float A[NS], h[NS], p[NS];
    #pragma unroll
    for (int q = 0; q < 4; ++q) {
        float4 av = *(const float4*)&A_logs[kd*NS + 4*q];
        A[4*q+0] = -expf(av.x); A[4*q+1] = -expf(av.y);
        A[4*q+2] = -expf(av.z); A[4*q+3] = -expf(av.w);
    }
    #pragma unroll
    for (int n = 0; n < NS; ++n) { h[n] = 0.f; p[n] = 1.f; }
    __syncthreads();

    const bool rev = (k >= 2);
    const float* dp = delta + ((size_t)bk*LL + c*CS)*DI + d;
    const float* up = ((k & 1) ? xs1 : xs0) + (size_t)b*LL*DI + d;
    const int l0 = c*CS;

    #pragma unroll 2
    for (int i = 0; i < CS; ++i) {
        float dt = dp[(size_t)i*DI];
        int lp = rev ? (LL-1-(l0+i)) : (l0+i);
        float u = up[(size_t)lp*DI];
        float dtu = dt * u;
        float Bv[NS];
        #pragma unroll
        for (int q = 0; q < 4; ++q)
            *(float4*)&Bv[4*q] = *(const float4*)&Bl[i*NS + 4*q];
        #pragma unroll
        for (int n = 0; n < NS; ++n) {
            float dA = __expf(dt * A[n]);
            h[n] = fmaf(dA, h[n], dtu * Bv[n]);
            p[n] *= dA;
        }
    }
    size_t obase = ((size_t)c*ROWS + bk*DI + d)*NS;
    #pragma unroll
    for (int q = 0; q < 4; ++q) {
        *(float4*)&P[obase + 4*q]    = make_float4(p[4*q], p[4*q+1], p[4*q+2], p[4*q+3]);
        *(float4*)&Hend[obase + 4*q] = make_float4(h[4*q], h[4*q+1], h[4*q+2], h[4*q+3]);
    }
}

// ------------- kernel 4b: combine chunk states sequentially -------------
__global__ __launch_bounds__(256) void k_scanmid(const float* __restrict__ P,
                                                 const float* __restrict__ Hend,
                                                 float* __restrict__ Hin) {
    int tid = blockIdx.x*256 + threadIdx.x;     // 0 .. ROWS*NS-1
    float h = 0.f;
    for (int c = 0; c < NC; ++c) {
        size_t idx = (size_t)c*(ROWS*NS) + tid;
        Hin[idx] = h;
        h = fmaf(P[idx], h, Hend[idx]);
    }
}

// ------------- kernel 4c: chunked scan pass 2 — rescan with true h_in, emit y -------------
__global__ __launch_bounds__(192) void k_scan2(const float* __restrict__ delta,
                                               const float* __restrict__ xs0,
                                               const float* __restrict__ xs1,
                                               const float* __restrict__ Bsb,
                                               const float* __restrict__ Csb,
                                               const float* __restrict__ A_logs,
                                               const float* __restrict__ Ds,
                                               const float* __restrict__ Hin,
                                               float* __restrict__ oy) {
    int c = blockIdx.x, bk = blockIdx.y;
    int k = bk & 3, b = bk >> 2;
    int d = threadIdx.x;
    int kd = k*DI + d;
    __shared__ float Bl[CS*NS];
    __shared__ float Cl[CS*NS];
    const float* bsrc = Bsb + ((size_t)bk*LL + c*CS)*NS;
    const float* csrc = Csb + ((size_t)bk*LL + c*CS)*NS;
    for (int i = threadIdx.x; i < CS*NS/4; i += 192) {
        ((float4*)Bl)[i] = ((const float4*)bsrc)[i];
        ((float4*)Cl)[i] = ((const float4*)csrc)[i];
    }

    float A[NS], h[NS];
    #pragma unroll
    for (int q = 0; q < 4; ++q) {
        float4 av = *(const float4*)&A_logs[kd*NS + 4*q];
        A[4*q+0] = -expf(av.x); A[4*q+1] = -expf(av.y);
        A[4*q+2] = -expf(av.z); A[4*q+3] = -expf(av.w);
    }
    size_t ibase = ((size_t)c*ROWS + bk*DI + d)*NS;
    #pragma unroll
    for (int q = 0; q < 4; ++q) {
        float4 hv = *(const float4*)&Hin[ibase + 4*q];
        h[4*q+0] = hv.x; h[4*q+1] = hv.y; h[4*q+2] = hv.z; h[4*q+3] = hv.w;
    }
    const float Dv = Ds[kd];
    __syncthreads();

    const bool rev = (k >= 2);
    const float* dp = delta + ((size_t)bk*LL + c*CS)*DI + d;
    const float* up = ((k & 1) ? xs1 : xs0) + (size_t)b*LL*DI + d;
    float* yp = oy + ((size_t)bk*LL + c*CS)*DI + d;
    const int l0 = c*CS;

    #pragma unroll 2
    for (int i = 0; i < CS; ++i) {
        float dt = dp[(size_t)i*DI];
        int lp = rev ? (LL-1-(l0+i)) : (l0+i);
        float u = up[(size_t)lp*DI];
        float dtu = dt * u;
        float Bv[NS], Cv[NS];
        #pragma unroll
        for (int q = 0; q < 4; ++q) {
            *(float4*)&Bv[4*q] = *(const float4*)&Bl[i*NS + 4*q];
            *(float4*)&Cv[4*q] = *(const float4*)&Cl[i*NS + 4*q];
        }
        float acc = 0.f;
        #pragma unroll
        for (int n = 0; n < NS; ++n) {
            float dA = __expf(dt * A[n]);
            h[n] = fmaf(dA, h[n], dtu * Bv[n]);
            acc = fmaf(h[n], Cv[n], acc);
        }
        yp[(size_t)i*DI] = fmaf(u, Dv, acc);
    }
}

// ------------- kernel 5: gather + LayerNorm + gate, then float4 GEMM out_proj -------------
#define OP_BM 32
__global__ __launch_bounds__(256) void k_out(const float* __restrict__ oy,
                                             const float* __restrict__ zsilu,
                                             const float* __restrict__ onw,
                                             const float* __restrict__ onb,
                                             const float* __restrict__ opw,
                                             float* __restrict__ out) {
    __shared__ float yv[OP_BM*196];
    __shared__ float wl[96*68];
    int t = threadIdx.x;
    int bl0 = blockIdx.x * OP_BM;
    int b = (blockIdx.x >= (LL/OP_BM)) ? 1 : 0;   // uniform, no div
    int lbase = bl0 - b*LL;
    int lane = t & 63, wv = t >> 6;

    for (int pp = 0; pp < 8; ++pp) {
        int p = wv*8 + pp;
        int l = lbase + p;
        int h = l / WW, w2 = l % WW;              // const-div -> mulhi
        int i = (w2 & 1) ? (HH-1-h) : h;
        int l0 = i*WW + w2;
        int l1 = ((i & 1) ? (WW-1-w2) : w2)*HH + i;
        size_t base = (size_t)b*KK*LL*DI;
        float yd[3]; float s1 = 0.f, s2 = 0.f;
        #pragma unroll
        for (int j = 0; j < 3; ++j) {
            int c = lane + j*64;
            float v = oy[base + (size_t)(0*LL + l0)*DI + c]
                    + oy[base + (size_t)(1*LL + l1)*DI + c]
                    + oy[base + (size_t)(2*LL + (LL-1-l0))*DI + c]
                    + oy[base + (size_t)(3*LL + (LL-1-l1))*DI + c];
            yd[j] = v; s1 += v; s2 += v*v;
        }
        #pragma unroll
        for (int m = 1; m < 64; m <<= 1) { s1 += __shfl_xor(s1, m); s2 += __shfl_xor(s2, m); }
        float mu  = s1 / DI;
        float var = s2 / DI - mu*mu;
        float ry  = rsqrtf(var + 1e-5f);
        #pragma unroll
        for (int j = 0; j < 3; ++j) {
            int c = lane + j*64;
            float yn = (yd[j] - mu) * ry * onw[c] + onb[c];
            yv[p*196 + c] = yn * zsilu[(size_t)(bl0+p)*DI + c];
        }
    }

    // phase B: 4p x 3e float4 micro-tile over 3 k-chunks of 64
    int pg = t >> 5, eg = t & 31;     // pg: 4 positions, eg: 3 channels
    float acc[4][3] = {};
    for (int kc = 0; kc < 3; ++kc) {
        __syncthreads();
        for (int r = t >> 4; r < 96; r += 16)
            *(float4*)&wl[r*68 + 4*(t&15)] =
                *(const float4*)&opw[(size_t)r*DI + kc*64 + 4*(t&15)];
        __syncthreads();
        const float4* y0 = (const float4*)&yv[(pg*4+0)*196 + kc*64];
        const float4* y1 = (const float4*)&yv[(pg*4+1)*196 + kc*64];
        const float4* y2 = (const float4*)&yv[(pg*4+2)*196 + kc*64];
        const float4* y3 = (const float4*)&yv[(pg*4+3)*196 + kc*64];
        const float4* w0 = (const float4*)&wl[(eg*3+0)*68];
        const float4* w1 = (const float4*)&wl[(eg*3+1)*68];
        const float4* w2 = (const float4*)&wl[(eg*3+2)*68];
        #pragma unroll
        for (int q = 0; q < 16; ++q) {
            float4 a0 = y0[q], a1 = y1[q], a2 = y2[q], a3 = y3[q];
            float4 b0 = w0[q], b1 = w1[q], b2 = w2[q];
            acc[0][0]=fmaf(a0.x,b0.x,acc[0][0]); acc[0][0]=fmaf(a0.y,b0.y,acc[0][0]);
            acc[0][0]=fmaf(a0.z,b0.z,acc[0][0]); acc[0][0]=fmaf(a0.w,b0.w,acc[0][0]);
            acc[0][1]=fmaf(a0.x,b1.x,acc[0][1]); acc[0][1]=fmaf(a0.y,b1.y,acc[0][1]);
            acc[0][1]=fmaf(a0.z,b1.z,acc[0][1]); acc[0][1]=fmaf(a0.w,b1.w,acc[0][1]);
            acc[0][2]=fmaf(a0.x,b2.x,acc[0][2]); acc[0][2]=fmaf(a0.y,b2.y,acc[0][2]);
            acc[0][2]=fmaf(a0.z,b2.z,acc[0][2]); acc[0][2]=fmaf(a0.w,b2.w,acc[0][2]);
            acc[1][0]=fmaf(a1.x,b0.x,acc[1][0]); acc[1][0]=fmaf(a1.y,b0.y,acc[1][0]);
            acc[1][0]=fmaf(a1.z,b0.z,acc[1][0]); acc[1][0]=fmaf(a1.w,b0.w,acc[1][0]);
            acc[1][1]=fmaf(a1.x,b1.x,acc[1][1]); acc[1][1]=fmaf(a1.y,b1.y,acc[1][1]);
            acc[1][1]=fmaf(a1.z,b1.z,acc[1][1]); acc[1][1]=fmaf(a1.w,b1.w,acc[1][1]);
            acc[1][2]=fmaf(a1.x,b2.x,acc[1][2]); acc[1][2]=fmaf(a1.y,b2.y,acc[1][2]);
            acc[1][2]=fmaf(a1.z,b2.z,acc[1][2]); acc[1][2]=fmaf(a1.w,b2.w,acc[1][2]);
            acc[2][0]=fmaf(a2.x,b0.x,acc[2][0]); acc[2][0]=fmaf(a2.y,b0.y,acc[2][0]);
            acc[2][0]=fmaf(a2.z,b0.z,acc[2][0]); acc[2][0]=fmaf(a2.w,b0.w,acc[2][0]);
            acc[2][1]=fmaf(a2.x,b1.x,acc[2][1]); acc[2][1]=fmaf(a2.y,b1.y,acc[2][1]);
            acc[2][1]=fmaf(a2.z,b1.z,acc[2][1]); acc[2][1]=fmaf(a2.w,b1.w,acc[2][1]);
            acc[2][2]=fmaf(a2.x,b2.x,acc[2][2]); acc[2][2]=fmaf(a2.y,b2.y,acc[2][2]);
            acc[2][2]=fmaf(a2.z,b2.z,acc[2][2]); acc[2][2]=fmaf(a2.w,b2.w,acc[2][2]);
            acc[3][0]=fmaf(a3.x,b0.x,acc[3][0]); acc[3][0]=fmaf(a3.y,b0.y,acc[3][0]);
            acc[3][0]=fmaf(a3.z,b0.z,acc[3][0]); acc[3][0]=fmaf(a3.w,b0.w,acc[3][0]);
            acc[3][1]=fmaf(a3.x,b1.x,acc[3][1]); acc[3][1]=fmaf(a3.y,b1.y,acc[3][1]);
            acc[3][1]=fmaf(a3.z,b1.z,acc[3][1]); acc[3][1]=fmaf(a3.w,b1.w,acc[3][1]);
            acc[3][2]=fmaf(a3.x,b2.x,acc[3][2]); acc[3][2]=fmaf(a3.y,b2.y,acc[3][2]);
            acc[3][2]=fmaf(a3.z,b2.z,acc[3][2]); acc[3][2]=fmaf(a3.w,b2.w,acc[3][2]);
        }
    }
    #pragma unroll
    for (int j = 0; j < 4; ++j) {
        int bl = bl0 + pg*4 + j;
        #pragma unroll
        for (int jj = 0; jj < 3; ++jj)
            out[(size_t)bl*DM + eg*3 + jj] = acc[j][jj];
    }
}

extern "C" void kernel_launch(void* const* d_in, const int* in_sizes, int n_in,
                              void* d_out, int out_size, void* d_ws, size_t ws_size,
                              hipStream_t stream) {
    const float* x      = (const float*)d_in[0];
    const float* ipw    = (const float*)d_in[1];
    const float* convw  = (const float*)d_in[2];
    const float* convb  = (const float*)d_in[3];
    const float* xpw    = (const float*)d_in[4];
    const float* dtw    = (const float*)d_in[5];
    const float* dtb    = (const float*)d_in[6];
    const float* A_logs = (const float*)d_in[7];
    const float* Ds     = (const float*)d_in[8];
    const float* onw    = (const float*)d_in[9];
    const float* onb    = (const float*)d_in[10];
    const float* opw    = (const float*)d_in[11];
    float* out = (float*)d_out;

    float* ws = (float*)d_ws;
    const size_t SZ_BLD  = (size_t)BB*LL*DI;          // 1,204,224
    const size_t SZ_BKLD = (size_t)BB*KK*LL*DI;       // 4,816,896
    const size_t SZ_BKLN = (size_t)BB*KK*LL*NS;       //   401,408
    const size_t SZ_ST   = (size_t)NC*ROWS*NS;        // 2,408,448
    float* xcpre = ws;
    float* zsilu = xcpre + SZ_BLD;
    float* xs0   = zsilu + SZ_BLD;
    float* xs1   = xs0   + SZ_BLD;
    float* delta = xs1   + SZ_BLD;
    float* Bsb   = delta + SZ_BKLD;
    float* Csb   = Bsb   + SZ_BKLN;
    float* oy    = Csb   + SZ_BKLN;
    float* Hin   = oy    + SZ_BKLD;
    float* Hend  = oy;                // alias: dead before oy written (scan2)
    float* P     = oy + SZ_ST;        // alias: 2*SZ_ST == SZ_BKLD, fits exactly

    k_inproj<<<(BB*LL)/IP_BM, 256, 0, stream>>>(x, ipw, xcpre, zsilu);
    k_conv<<<dim3(WW, HH, BB), DI, 0, stream>>>(xcpre, convw, convb, xs0, xs1);
    dim3 g3(LL/TL, KK, BB);
    k_proj<<<g3, 256, 0, stream>>>(xs0, xs1, xpw, dtw, dtb, delta, Bsb, Csb);
    dim3 gs(NC, BB*KK);
    k_scan1<<<gs, 192, 0, stream>>>(delta, xs0, xs1, Bsb, A_logs, P, Hend);
    k_scanmid<<<(ROWS*NS)/256, 256, 0, stream>>>(P, Hend, Hin);
    k_scan2<<<gs, 192, 0, stream>>>(delta, xs0, xs1, Bsb, Csb, A_logs, Ds, Hin, oy);
    k_out<<<(BB*LL)/OP_BM, 256, 0, stream>>>(oy, zsilu, onw, onb, opw, out);
}

// Round 11
// 223.678 us; speedup vs baseline: 1.1584x; 1.0929x over previous
//
#include <hip/hip_runtime.h>
#include <hip/hip_bf16.h>

#define BB 2
#define HH 56
#define WW 56
#define LL (HH*WW)          // 3136
#define DM 96
#define DI 192
#define NS 16               // d_state
#define DTR 6
#define KK 4
#define CDBL (DTR + 2*NS)   // 38
#define CS 32               // scan chunk size
#define NC 98               // number of chunks (CS*NC == LL)
#define ROWS (BB*KK*DI)     // 1536 state rows (x NS cols) per chunk

// ---------------- kernel 1: in_proj tiled GEMM, grid split over 6 output chunks ----------------
// grid (196, 6): block = 32 positions x 64 output channels (one chunk). ~4.6 blocks/CU.
#define IP_BM 32
__global__ __launch_bounds__(256) void k_inproj(const float* __restrict__ x,
                                                const float* __restrict__ w,
                                                float* __restrict__ xcpre,
                                                float* __restrict__ zsilu) {
    __shared__ float xl[IP_BM*100];   // [pos][96], stride 100
    __shared__ float wl[64*100];      // j-interleaved: w-row r at lds row (r&3)*16+(r>>2)
    int t = threadIdx.x;
    int bl0 = blockIdx.x * IP_BM;
    int nc = blockIdx.y;
    int qs = t & 31;                  // staging q (0..23 active)
    for (int r = t >> 5; r < IP_BM; r += 8)
        if (qs < 24)
            *(float4*)&xl[r*100 + 4*qs] = *(const float4*)&x[(size_t)(bl0+r)*DM + 4*qs];
    for (int r = t >> 5; r < 64; r += 8)
        if (qs < 24)
            *(float4*)&wl[((r&3)*16 + (r>>2))*100 + 4*qs] =
                *(const float4*)&w[(size_t)(nc*64+r)*DM + 4*qs];
    __syncthreads();

    int pg = t >> 4, eg = t & 15;     // pg: 2 positions, eg: 4 channels (eg*4+j)
    float acc[2][4] = {};
    const float4* xa4 = (const float4*)&xl[(pg*2+0)*100];
    const float4* xb4 = (const float4*)&xl[(pg*2+1)*100];
    const float4* w0 = (const float4*)&wl[(0*16+eg)*100];
    const float4* w1 = (const float4*)&wl[(1*16+eg)*100];
    const float4* w2 = (const float4*)&wl[(2*16+eg)*100];
    const float4* w3 = (const float4*)&wl[(3*16+eg)*100];
    #pragma unroll 6
    for (int q = 0; q < 24; ++q) {
        float4 xa = xa4[q], xb = xb4[q];
        float4 b0 = w0[q], b1 = w1[q], b2 = w2[q], b3 = w3[q];
        acc[0][0]=fmaf(xa.x,b0.x,acc[0][0]); acc[0][0]=fmaf(xa.y,b0.y,acc[0][0]);
        acc[0][0]=fmaf(xa.z,b0.z,acc[0][0]); acc[0][0]=fmaf(xa.w,b0.w,acc[0][0]);
        acc[0][1]=fmaf(xa.x,b1.x,acc[0][1]); acc[0][1]=fmaf(xa.y,b1.y,acc[0][1]);
        acc[0][1]=fmaf(xa.z,b1.z,acc[0][1]); acc[0][1]=fmaf(xa.w,b1.w,acc[0][1]);
        acc[0][2]=fmaf(xa.x,b2.x,acc[0][2]); acc[0][2]=fmaf(xa.y,b2.y,acc[0][2]);
        acc[0][2]=fmaf(xa.z,b2.z,acc[0][2]); acc[0][2]=fmaf(xa.w,b2.w,acc[0][2]);
        acc[0][3]=fmaf(xa.x,b3.x,acc[0][3]); acc[0][3]=fmaf(xa.y,b3.y,acc[0][3]);
        acc[0][3]=fmaf(xa.z,b3.z,acc[0][3]); acc[0][3]=fmaf(xa.w,b3.w,acc[0][3]);
        acc[1][0]=fmaf(xb.x,b0.x,acc[1][0]); acc[1][0]=fmaf(xb.y,b0.y,acc[1][0]);
        acc[1][0]=fmaf(xb.z,b0.z,acc[1][0]); acc[1][0]=fmaf(xb.w,b0.w,acc[1][0]);
        acc[1][1]=fmaf(xb.x,b1.x,acc[1][1]); acc[1][1]=fmaf(xb.y,b1.y,acc[1][1]);
        acc[1][1]=fmaf(xb.z,b1.z,acc[1][1]); acc[1][1]=fmaf(xb.w,b1.w,acc[1][1]);
        acc[1][2]=fmaf(xb.x,b2.x,acc[1][2]); acc[1][2]=fmaf(xb.y,b2.y,acc[1][2]);
        acc[1][2]=fmaf(xb.z,b2.z,acc[1][2]); acc[1][2]=fmaf(xb.w,b2.w,acc[1][2]);
        acc[1][3]=fmaf(xb.x,b3.x,acc[1][3]); acc[1][3]=fmaf(xb.y,b3.y,acc[1][3]);
        acc[1][3]=fmaf(xb.z,b3.z,acc[1][3]); acc[1][3]=fmaf(xb.w,b3.w,acc[1][3]);
    }
    if (nc < 3) {
        #pragma unroll
        for (int j = 0; j < 2; ++j) {
            int bl = bl0 + pg*2 + j;
            #pragma unroll
            for (int jj = 0; jj < 4; ++jj)
                xcpre[(size_t)bl*DI + nc*64 + eg*4 + jj] = acc[j][jj];
        }
    } else {
        #pragma unroll
        for (int j = 0; j < 2; ++j) {
            int bl = bl0 + pg*2 + j;
            #pragma unroll
            for (int jj = 0; jj < 4; ++jj) {
                float v = acc[j][jj];
                zsilu[(size_t)bl*DI + (nc-3)*64 + eg*4 + jj] = v / (1.f + __expf(-v));
            }
        }
    }
}

// ------------- kernel 2: depthwise 3x3 conv + silu + scan scatter (no div) -------------
__global__ __launch_bounds__(DI) void k_conv(const float* __restrict__ xcpre,
                                             const float* __restrict__ cw,
                                             const float* __restrict__ cb,
                                             float* __restrict__ xs0,
                                             float* __restrict__ xs1) {
    int w = blockIdx.x, h = blockIdx.y, b = blockIdx.z;
    int c = threadIdx.x;
    const float* src = xcpre + ((size_t)(b*LL + h*WW + w))*DI + c;
    const float* cwc = cw + c*9;
    float acc = cb[c];
    if (h > 0) {
        if (w > 0)      acc = fmaf(src[-(WW+1)*DI], cwc[0], acc);
                        acc = fmaf(src[-WW*DI],     cwc[1], acc);
        if (w < WW-1)   acc = fmaf(src[-(WW-1)*DI], cwc[2], acc);
    }
    {
        if (w > 0)      acc = fmaf(src[-DI],        cwc[3], acc);
                        acc = fmaf(src[0],          cwc[4], acc);
        if (w < WW-1)   acc = fmaf(src[DI],         cwc[5], acc);
    }
    if (h < HH-1) {
        if (w > 0)      acc = fmaf(src[(WW-1)*DI],  cwc[6], acc);
                        acc = fmaf(src[WW*DI],      cwc[7], acc);
        if (w < WW-1)   acc = fmaf(src[(WW+1)*DI],  cwc[8], acc);
    }
    float v = acc / (1.f + __expf(-acc));   // silu
    int i  = (w & 1) ? (HH-1-h) : h;
    int l0 = i*WW + w;
    int l1 = ((i & 1) ? (WW-1-w) : w)*HH + i;
    xs0[((size_t)b*LL + l0)*DI + c] = v;
    xs1[((size_t)b*LL + l1)*DI + c] = v;
}

// ------------- kernel 3: x_proj + dt_proj + softplus (overhead-stripped) -------------
#define TL 32
#define KCH 48
#define NKC 4
#define LSTR 52
__global__ __launch_bounds__(256) void k_proj(const float* __restrict__ xs0,
                                              const float* __restrict__ xs1,
                                              const float* __restrict__ xpw,   // (K,38,192)
                                              const float* __restrict__ dtw,   // (K,192,6)
                                              const float* __restrict__ dtb,   // (K,192)
                                              float* __restrict__ delta,
                                              float* __restrict__ Bsb,
                                              float* __restrict__ Csb) {
    int tile = blockIdx.x, k = blockIdx.y, b = blockIdx.z;
    int bk = b*KK + k;
    int t = threadIdx.x;
    __shared__ float Xl[TL*LSTR];
    __shared__ float Wl[39*LSTR];
    __shared__ float dblL[DTR*36];

    const float* src = (k & 1) ? xs1 : xs0;
    const bool rev = (k >= 2);
    int cp = t >> 4, lp = t & 15;
    int qs = t & 15;                  // staging q (0..11 active)

    float acc[3][2] = {};
    for (int kc = 0; kc < NKC; ++kc) {
        __syncthreads();
        // stage Wl: 39 rows x 12 float4 (row 38 zero) — shift/mask indexing
        for (int r = t >> 4; r < 39; r += 16)
            if (qs < 12) {
                float4 v = (r < CDBL)
                    ? *(const float4*)&xpw[(size_t)k*CDBL*DI + (size_t)r*DI + kc*KCH + 4*qs]
                    : make_float4(0.f,0.f,0.f,0.f);
                *(float4*)&Wl[r*LSTR + 4*qs] = v;
            }
        // stage Xl: 32 rows x 12 float4
        for (int r = t >> 4; r < TL; r += 16)
            if (qs < 12) {
                int lg = tile*TL + r;
                int lpos = rev ? (LL-1-lg) : lg;
                *(float4*)&Xl[r*LSTR + 4*qs] =
                    *(const float4*)&src[(size_t)(b*LL + lpos)*DI + kc*KCH + 4*qs];
            }
        __syncthreads();
        if (cp < 13) {
            const float4* w0 = (const float4*)&Wl[(3*cp+0)*LSTR];
            const float4* w1 = (const float4*)&Wl[(3*cp+1)*LSTR];
            const float4* w2 = (const float4*)&Wl[(3*cp+2)*LSTR];
            const float4* x0 = (const float4*)&Xl[(lp    )*LSTR];
            const float4* x1 = (const float4*)&Xl[(lp+16)*LSTR];
            #pragma unroll
            for (int q = 0; q < 12; ++q) {
                float4 wa = w0[q], wb = w1[q], wc = w2[q];
                float4 xa = x0[q], xb = x1[q];
                acc[0][0]=fmaf(wa.x,xa.x,acc[0][0]); acc[0][0]=fmaf(wa.y,xa.y,acc[0][0]);
                acc[0][0]=fmaf(wa.z,xa.z,acc[0][0]); acc[0][0]=fmaf(wa.w,xa.w,acc[0][0]);
                acc[0][1]=fmaf(wa.x,xb.x,acc[0][1]); acc[0][1]=fmaf(wa.y,xb.y,acc[0][1]);
                acc[0][1]=fmaf(wa.z,xb.z,acc[0][1]); acc[0][1]=fmaf(wa.w,xb.w,acc[0][1]);
                acc[1][0]=fmaf(wb.x,xa.x,acc[1][0]); acc[1][0]=fmaf(wb.y,xa.y,acc[1][0]);
                acc[1][0]=fmaf(wb.z,xa.z,acc[1][0]); acc[1][0]=fmaf(wb.w,xa.w,acc[1][0]);
                acc[1][1]=fmaf(wb.x,xb.x,acc[1][1]); acc[1][1]=fmaf(wb.y,xb.y,acc[1][1]);
                acc[1][1]=fmaf(wb.z,xb.z,acc[1][1]); acc[1][1]=fmaf(wb.w,xb.w,acc[1][1]);
                acc[2][0]=fmaf(wc.x,xa.x,acc[2][0]); acc[2][0]=fmaf(wc.y,xa.y,acc[2][0]);
                acc[2][0]=fmaf(wc.z,xa.z,acc[2][0]); acc[2][0]=fmaf(wc.w,xa.w,acc[2][0]);
                acc[2][1]=fmaf(wc.x,xb.x,acc[2][1]); acc[2][1]=fmaf(wc.y,xb.y,acc[2][1]);
                acc[2][1]=fmaf(wc.z,xb.z,acc[2][1]); acc[2][1]=fmaf(wc.w,xb.w,acc[2][1]);
            }
        }
    }
    if (cp < 13) {
        #pragma unroll
        for (int ci = 0; ci < 3; ++ci) {
            int c = 3*cp + ci;
            if (c < CDBL) {
                #pragma unroll
                for (int li = 0; li < 2; ++li) {
                    int ll = lp + 16*li;
                    int lg = tile*TL + ll;
                    float v = acc[ci][li];
                    if (c < DTR)          dblL[c*36 + ll] = v;
                    else if (c < DTR+NS)  Bsb[((size_t)bk*LL + lg)*NS + (c-DTR)] = v;
                    else                  Csb[((size_t)bk*LL + lg)*NS + (c-DTR-NS)] = v;
                }
            }
        }
    }
    __syncthreads();

    // phase 2: thread = d (192 active), acc[32] in regs, no div, fast softplus
    if (t < DI) {
        int d = t;
        float wr[DTR];
        #pragma unroll
        for (int r = 0; r < DTR; ++r) wr[r] = dtw[((size_t)k*DI + d)*DTR + r];
        float bias = dtb[k*DI + d];
        float a2[TL];
        #pragma unroll
        for (int ll = 0; ll < TL; ++ll) a2[ll] = bias;
        #pragma unroll
        for (int r = 0; r < DTR; ++r) {
            float wv = wr[r];
            const float4* db = (const float4*)&dblL[r*36];
            #pragma unroll
            for (int q = 0; q < 8; ++q) {
                float4 v = db[q];
                a2[4*q+0] = fmaf(wv, v.x, a2[4*q+0]);
                a2[4*q+1] = fmaf(wv, v.y, a2[4*q+1]);
                a2[4*q+2] = fmaf(wv, v.z, a2[4*q+2]);
                a2[4*q+3] = fmaf(wv, v.w, a2[4*q+3]);
            }
        }
        float* dst = delta + ((size_t)bk*LL + (size_t)tile*TL)*DI + d;
        #pragma unroll
        for (int ll = 0; ll < TL; ++ll) {
            float a = a2[ll];
            float sp = fmaxf(a, 0.f) + __logf(1.f + __expf(-fabsf(a)));
            dst[ll*DI] = sp;
        }
    }
}

// ------------- kernel 4a: chunked scan pass 1 — thread = d, 16 n-states in regs -------------
__global__ __launch_bounds__(192) void k_scan1(const float* __restrict__ delta,
                                               const float* __restrict__ xs0,
                                               const float* __restrict__ xs1,
                                               const float* __restrict__ Bsb,
                                               const float* __restrict__ A_logs,
                                               float* __restrict__ P,     // [c][bk*DI+d][n]
                                               float* __restrict__ Hend) {
    int c = blockIdx.x, bk = blockIdx.y;
    int k = bk & 3, b = bk >> 2;
    int d = threadIdx.x;
    int kd = k*DI + d;
    __shared__ float Bl[CS*NS];
    const float* bsrc = Bsb + ((size_t)bk*LL + c*CS)*NS;
    for (int i = threadIdx.x; i < CS*NS/4; i += 192)
        ((float4*)Bl)[i] = ((const float4*)bsrc)[i];

    float A[NS], h[NS], p[NS];
    #pragma unroll
    for (int q = 0; q < 4; ++q) {
        float4 av = *(const float4*)&A_logs[kd*NS + 4*q];
        A[4*q+0] = -expf(av.x); A[4*q+1] = -expf(av.y);
        A[4*q+2] = -expf(av.z); A[4*q+3] = -expf(av.w);
    }
    #pragma unroll
    for (int n = 0; n < NS; ++n) { h[n] = 0.f; p[n] = 1.f; }
    __syncthreads();

    const bool rev = (k >= 2);
    const float* dp = delta + ((size_t)bk*LL + c*CS)*DI + d;
    const float* up = ((k & 1) ? xs1 : xs0) + (size_t)b*LL*DI + d;
    const int l0 = c*CS;

    #pragma unroll 2
    for (int i = 0; i < CS; ++i) {
        float dt = dp[(size_t)i*DI];
        int lp = rev ? (LL-1-(l0+i)) : (l0+i);
        float u = up[(size_t)lp*DI];
        float dtu = dt * u;
        float Bv[NS];
        #pragma unroll
        for (int q = 0; q < 4; ++q)
            *(float4*)&Bv[4*q] = *(const float4*)&Bl[i*NS + 4*q];
        #pragma unroll
        for (int n = 0; n < NS; ++n) {
            float dA = __expf(dt * A[n]);
            h[n] = fmaf(dA, h[n], dtu * Bv[n]);
            p[n] *= dA;
        }
    }
    size_t obase = ((size_t)c*ROWS + bk*DI + d)*NS;
    #pragma unroll
    for (int q = 0; q < 4; ++q) {
        *(float4*)&P[obase + 4*q]    = make_float4(p[4*q], p[4*q+1], p[4*q+2], p[4*q+3]);
        *(float4*)&Hend[obase + 4*q] = make_float4(h[4*q], h[4*q+1], h[4*q+2], h[4*q+3]);
    }
}

// ------------- kernel 4b: combine chunk states sequentially -------------
__global__ __launch_bounds__(256) void k_scanmid(const float* __restrict__ P,
                                                 const float* __restrict__ Hend,
                                                 float* __restrict__ Hin) {
    int tid = blockIdx.x*256 + threadIdx.x;     // 0 .. ROWS*NS-1
    float h = 0.f;
    for (int c = 0; c < NC; ++c) {
        size_t idx = (size_t)c*(ROWS*NS) + tid;
        Hin[idx] = h;
        h = fmaf(P[idx], h, Hend[idx]);
    }
}

// ------------- kernel 4c: chunked scan pass 2 — rescan with true h_in, emit y -------------
__global__ __launch_bounds__(192) void k_scan2(const float* __restrict__ delta,
                                               const float* __restrict__ xs0,
                                               const float* __restrict__ xs1,
                                               const float* __restrict__ Bsb,
                                               const float* __restrict__ Csb,
                                               const float* __restrict__ A_logs,
                                               const float* __restrict__ Ds,
                                               const float* __restrict__ Hin,
                                               float* __restrict__ oy) {
    int c = blockIdx.x, bk = blockIdx.y;
    int k = bk & 3, b = bk >> 2;
    int d = threadIdx.x;
    int kd = k*DI + d;
    __shared__ float Bl[CS*NS];
    __shared__ float Cl[CS*NS];
    const float* bsrc = Bsb + ((size_t)bk*LL + c*CS)*NS;
    const float* csrc = Csb + ((size_t)bk*LL + c*CS)*NS;
    for (int i = threadIdx.x; i < CS*NS/4; i += 192) {
        ((float4*)Bl)[i] = ((const float4*)bsrc)[i];
        ((float4*)Cl)[i] = ((const float4*)csrc)[i];
    }

    float A[NS], h[NS];
    #pragma unroll
    for (int q = 0; q < 4; ++q) {
        float4 av = *(const float4*)&A_logs[kd*NS + 4*q];
        A[4*q+0] = -expf(av.x); A[4*q+1] = -expf(av.y);
        A[4*q+2] = -expf(av.z); A[4*q+3] = -expf(av.w);
    }
    size_t ibase = ((size_t)c*ROWS + bk*DI + d)*NS;
    #pragma unroll
    for (int q = 0; q < 4; ++q) {
        float4 hv = *(const float4*)&Hin[ibase + 4*q];
        h[4*q+0] = hv.x; h[4*q+1] = hv.y; h[4*q+2] = hv.z; h[4*q+3] = hv.w;
    }
    const float Dv = Ds[kd];
    __syncthreads();

    const bool rev = (k >= 2);
    const float* dp = delta + ((size_t)bk*LL + c*CS)*DI + d;
    const float* up = ((k & 1) ? xs1 : xs0) + (size_t)b*LL*DI + d;
    float* yp = oy + ((size_t)bk*LL + c*CS)*DI + d;
    const int l0 = c*CS;

    #pragma unroll 2
    for (int i = 0; i < CS; ++i) {
        float dt = dp[(size_t)i*DI];
        int lp = rev ? (LL-1-(l0+i)) : (l0+i);
        float u = up[(size_t)lp*DI];
        float dtu = dt * u;
        float Bv[NS], Cv[NS];
        #pragma unroll
        for (int q = 0; q < 4; ++q) {
            *(float4*)&Bv[4*q] = *(const float4*)&Bl[i*NS + 4*q];
            *(float4*)&Cv[4*q] = *(const float4*)&Cl[i*NS + 4*q];
        }
        float acc = 0.f;
        #pragma unroll
        for (int n = 0; n < NS; ++n) {
            float dA = __expf(dt * A[n]);
            h[n] = fmaf(dA, h[n], dtu * Bv[n]);
            acc = fmaf(h[n], Cv[n], acc);
        }
        yp[(size_t)i*DI] = fmaf(u, Dv, acc);
    }
}

// ------------- kernel 5: gather + LayerNorm + gate, then float4 GEMM out_proj -------------
#define OP_BM 32
__global__ __launch_bounds__(256) void k_out(const float* __restrict__ oy,
                                             const float* __restrict__ zsilu,
                                             const float* __restrict__ onw,
                                             const float* __restrict__ onb,
                                             const float* __restrict__ opw,
                                             float* __restrict__ out) {
    __shared__ float yv[OP_BM*196];
    __shared__ float wl[96*68];
    int t = threadIdx.x;
    int bl0 = blockIdx.x * OP_BM;
    int b = (blockIdx.x >= (LL/OP_BM)) ? 1 : 0;   // uniform, no div
    int lbase = bl0 - b*LL;
    int lane = t & 63, wv = t >> 6;

    for (int pp = 0; pp < 8; ++pp) {
        int p = wv*8 + pp;
        int l = lbase + p;
        int h = l / WW, w2 = l % WW;              // const-div -> mulhi
        int i = (w2 & 1) ? (HH-1-h) : h;
        int l0 = i*WW + w2;
        int l1 = ((i & 1) ? (WW-1-w2) : w2)*HH + i;
        size_t base = (size_t)b*KK*LL*DI;
        float yd[3]; float s1 = 0.f, s2 = 0.f;
        #pragma unroll
        for (int j = 0; j < 3; ++j) {
            int c = lane + j*64;
            float v = oy[base + (size_t)(0*LL + l0)*DI + c]
                    + oy[base + (size_t)(1*LL + l1)*DI + c]
                    + oy[base + (size_t)(2*LL + (LL-1-l0))*DI + c]
                    + oy[base + (size_t)(3*LL + (LL-1-l1))*DI + c];
            yd[j] = v; s1 += v; s2 += v*v;
        }
        #pragma unroll
        for (int m = 1; m < 64; m <<= 1) { s1 += __shfl_xor(s1, m); s2 += __shfl_xor(s2, m); }
        float mu  = s1 / DI;
        float var = s2 / DI - mu*mu;
        float ry  = rsqrtf(var + 1e-5f);
        #pragma unroll
        for (int j = 0; j < 3; ++j) {
            int c = lane + j*64;
            float yn = (yd[j] - mu) * ry * onw[c] + onb[c];
            yv[p*196 + c] = yn * zsilu[(size_t)(bl0+p)*DI + c];
        }
    }

    // phase B: 4p x 3e float4 micro-tile over 3 k-chunks of 64
    int pg = t >> 5, eg = t & 31;     // pg: 4 positions, eg: 3 channels
    float acc[4][3] = {};
    for (int kc = 0; kc < 3; ++kc) {
        __syncthreads();
        for (int r = t >> 4; r < 96; r += 16)
            *(float4*)&wl[r*68 + 4*(t&15)] =
                *(const float4*)&opw[(size_t)r*DI + kc*64 + 4*(t&15)];
        __syncthreads();
        const float4* y0 = (const float4*)&yv[(pg*4+0)*196 + kc*64];
        const float4* y1 = (const float4*)&yv[(pg*4+1)*196 + kc*64];
        const float4* y2 = (const float4*)&yv[(pg*4+2)*196 + kc*64];
        const float4* y3 = (const float4*)&yv[(pg*4+3)*196 + kc*64];
        const float4* w0 = (const float4*)&wl[(eg*3+0)*68];
        const float4* w1 = (const float4*)&wl[(eg*3+1)*68];
        const float4* w2 = (const float4*)&wl[(eg*3+2)*68];
        #pragma unroll
        for (int q = 0; q < 16; ++q) {
            float4 a0 = y0[q], a1 = y1[q], a2 = y2[q], a3 = y3[q];
            float4 b0 = w0[q], b1 = w1[q], b2 = w2[q];
            acc[0][0]=fmaf(a0.x,b0.x,acc[0][0]); acc[0][0]=fmaf(a0.y,b0.y,acc[0][0]);
            acc[0][0]=fmaf(a0.z,b0.z,acc[0][0]); acc[0][0]=fmaf(a0.w,b0.w,acc[0][0]);
            acc[0][1]=fmaf(a0.x,b1.x,acc[0][1]); acc[0][1]=fmaf(a0.y,b1.y,acc[0][1]);
            acc[0][1]=fmaf(a0.z,b1.z,acc[0][1]); acc[0][1]=fmaf(a0.w,b1.w,acc[0][1]);
            acc[0][2]=fmaf(a0.x,b2.x,acc[0][2]); acc[0][2]=fmaf(a0.y,b2.y,acc[0][2]);
            acc[0][2]=fmaf(a0.z,b2.z,acc[0][2]); acc[0][2]=fmaf(a0.w,b2.w,acc[0][2]);
            acc[1][0]=fmaf(a1.x,b0.x,acc[1][0]); acc[1][0]=fmaf(a1.y,b0.y,acc[1][0]);
            acc[1][0]=fmaf(a1.z,b0.z,acc[1][0]); acc[1][0]=fmaf(a1.w,b0.w,acc[1][0]);
            acc[1][1]=fmaf(a1.x,b1.x,acc[1][1]); acc[1][1]=fmaf(a1.y,b1.y,acc[1][1]);
            acc[1][1]=fmaf(a1.z,b1.z,acc[1][1]); acc[1][1]=fmaf(a1.w,b1.w,acc[1][1]);
            acc[1][2]=fmaf(a1.x,b2.x,acc[1][2]); acc[1][2]=fmaf(a1.y,b2.y,acc[1][2]);
            acc[1][2]=fmaf(a1.z,b2.z,acc[1][2]); acc[1][2]=fmaf(a1.w,b2.w,acc[1][2]);
            acc[2][0]=fmaf(a2.x,b0.x,acc[2][0]); acc[2][0]=fmaf(a2.y,b0.y,acc[2][0]);
            acc[2][0]=fmaf(a2.z,b0.z,acc[2][0]); acc[2][0]=fmaf(a2.w,b0.w,acc[2][0]);
            acc[2][1]=fmaf(a2.x,b1.x,acc[2][1]); acc[2][1]=fmaf(a2.y,b1.y,acc[2][1]);
            acc[2][1]=fmaf(a2.z,b1.z,acc[2][1]); acc[2][1]=fmaf(a2.w,b1.w,acc[2][1]);
            acc[2][2]=fmaf(a2.x,b2.x,acc[2][2]); acc[2][2]=fmaf(a2.y,b2.y,acc[2][2]);
            acc[2][2]=fmaf(a2.z,b2.z,acc[2][2]); acc[2][2]=fmaf(a2.w,b2.w,acc[2][2]);
            acc[3][0]=fmaf(a3.x,b0.x,acc[3][0]); acc[3][0]=fmaf(a3.y,b0.y,acc[3][0]);
            acc[3][0]=fmaf(a3.z,b0.z,acc[3][0]); acc[3][0]=fmaf(a3.w,b0.w,acc[3][0]);
            acc[3][1]=fmaf(a3.x,b1.x,acc[3][1]); acc[3][1]=fmaf(a3.y,b1.y,acc[3][1]);
            acc[3][1]=fmaf(a3.z,b1.z,acc[3][1]); acc[3][1]=fmaf(a3.w,b1.w,acc[3][1]);
            acc[3][2]=fmaf(a3.x,b2.x,acc[3][2]); acc[3][2]=fmaf(a3.y,b2.y,acc[3][2]);
            acc[3][2]=fmaf(a3.z,b2.z,acc[3][2]); acc[3][2]=fmaf(a3.w,b2.w,acc[3][2]);
        }
    }
    #pragma unroll
    for (int j = 0; j < 4; ++j) {
        int bl = bl0 + pg*4 + j;
        #pragma unroll
        for (int jj = 0; jj < 3; ++jj)
            out[(size_t)bl*DM + eg*3 + jj] = acc[j][jj];
    }
}

extern "C" void kernel_launch(void* const* d_in, const int* in_sizes, int n_in,
                              void* d_out, int out_size, void* d_ws, size_t ws_size,
                              hipStream_t stream) {
    const float* x      = (const float*)d_in[0];
    const float* ipw    = (const float*)d_in[1];
    const float* convw  = (const float*)d_in[2];
    const float* convb  = (const float*)d_in[3];
    const float* xpw    = (const float*)d_in[4];
    const float* dtw    = (const float*)d_in[5];
    const float* dtb    = (const float*)d_in[6];
    const float* A_logs = (const float*)d_in[7];
    const float* Ds     = (const float*)d_in[8];
    const float* onw    = (const float*)d_in[9];
    const float* onb    = (const float*)d_in[10];
    const float* opw    = (const float*)d_in[11];
    float* out = (float*)d_out;

    float* ws = (float*)d_ws;
    const size_t SZ_BLD  = (size_t)BB*LL*DI;          // 1,204,224
    const size_t SZ_BKLD = (size_t)BB*KK*LL*DI;       // 4,816,896
    const size_t SZ_BKLN = (size_t)BB*KK*LL*NS;       //   401,408
    const size_t SZ_ST   = (size_t)NC*ROWS*NS;        // 2,408,448
    float* xcpre = ws;
    float* zsilu = xcpre + SZ_BLD;
    float* xs0   = zsilu + SZ_BLD;
    float* xs1   = xs0   + SZ_BLD;
    float* delta = xs1   + SZ_BLD;
    float* Bsb   = delta + SZ_BKLD;
    float* Csb   = Bsb   + SZ_BKLN;
    float* oy    = Csb   + SZ_BKLN;
    float* Hin   = oy    + SZ_BKLD;
    float* Hend  = oy;                // alias: dead before oy written (scan2)
    float* P     = oy + SZ_ST;        // alias: 2*SZ_ST == SZ_BKLD, fits exactly

    k_inproj<<<dim3((BB*LL)/IP_BM, 6), 256, 0, stream>>>(x, ipw, xcpre, zsilu);
    k_conv<<<dim3(WW, HH, BB), DI, 0, stream>>>(xcpre, convw, convb, xs0, xs1);
    dim3 g3(LL/TL, KK, BB);
    k_proj<<<g3, 256, 0, stream>>>(xs0, xs1, xpw, dtw, dtb, delta, Bsb, Csb);
    dim3 gs(NC, BB*KK);
    k_scan1<<<gs, 192, 0, stream>>>(delta, xs0, xs1, Bsb, A_logs, P, Hend);
    k_scanmid<<<(ROWS*NS)/256, 256, 0, stream>>>(P, Hend, Hin);
    k_scan2<<<gs, 192, 0, stream>>>(delta, xs0, xs1, Bsb, Csb, A_logs, Ds, Hin, oy);
    k_out<<<(BB*LL)/OP_BM, 256, 0, stream>>>(oy, zsilu, onw, onb, opw, out);
}